// Round 1
// baseline (579.698 us; speedup 1.0000x reference)
//
#include <hip/hip_runtime.h>
#include <math.h>

#define BATCH 16
#define CH 64
#define HH 256
#define WW 256
#define HW (HH*WW)     // 65536
#define HW4 (HW/4)     // 16384
#define HIDDEN 32

// K1: per-pixel channel reductions: mean, max, xr = sum_c wr[c]*x[c]
__global__ __launch_bounds__(256) void k1_reduce(
    const float* __restrict__ x, const float* __restrict__ wr,
    float* __restrict__ meanp, float* __restrict__ maxp, float* __restrict__ xrp)
{
    int idx = blockIdx.x * 256 + threadIdx.x;   // [0, BATCH*HW4)
    int b = idx / HW4;
    int p = idx % HW4;
    const float4* xb = (const float4*)x + (size_t)b * CH * HW4 + p;
    float sx = 0.f, sy = 0.f, sz = 0.f, sw = 0.f;
    float mx = -3.4e38f, my = -3.4e38f, mz = -3.4e38f, mw = -3.4e38f;
    float rx = 0.f, ry = 0.f, rz = 0.f, rw = 0.f;
    #pragma unroll 4
    for (int c = 0; c < CH; c++) {
        float4 v = xb[(size_t)c * HW4];
        float w = wr[c];
        sx += v.x; sy += v.y; sz += v.z; sw += v.w;
        mx = fmaxf(mx, v.x); my = fmaxf(my, v.y); mz = fmaxf(mz, v.z); mw = fmaxf(mw, v.w);
        rx += w * v.x; ry += w * v.y; rz += w * v.z; rw += w * v.w;
    }
    const float inv = 1.0f / CH;
    size_t o = (size_t)b * HW4 + p;
    float4 mn = {sx * inv, sy * inv, sz * inv, sw * inv};
    float4 mxv = {mx, my, mz, mw};
    float4 xrv = {rx, ry, rz, rw};
    ((float4*)meanp)[o] = mn;
    ((float4*)maxp)[o] = mxv;
    ((float4*)xrp)[o] = xrv;
}

// K2: 3x3 + 5x5 convs over [mean,max] descriptor, sigmoid, 1x1 fuse, scale;
// writes f plane and accumulates sum_b( f * xr ) for the global pool.
__global__ __launch_bounds__(256) void k2_fused(
    const float* __restrict__ meanp, const float* __restrict__ maxp,
    const float* __restrict__ xrp,
    const float* __restrict__ w3, const float* __restrict__ b3,
    const float* __restrict__ w5, const float* __restrict__ b5,
    const float* __restrict__ wf, const float* __restrict__ bf,
    float* __restrict__ fplane, float* __restrict__ sums)
{
    __shared__ float sm[2][20][20];   // 16x16 tile + halo 2
    __shared__ float red[256];
    int b = blockIdx.z;
    int h0 = blockIdx.y * 16, w0 = blockIdx.x * 16;
    int tx = threadIdx.x, ty = threadIdx.y;
    int tid = ty * 16 + tx;
    const float* mb = meanp + (size_t)b * HW;
    const float* xb = maxp + (size_t)b * HW;
    for (int l = tid; l < 400; l += 256) {
        int lh = l / 20, lw = l % 20;
        int gh = h0 + lh - 2, gw = w0 + lw - 2;
        float vm = 0.f, vx = 0.f;
        if (gh >= 0 && gh < HH && gw >= 0 && gw < WW) {
            vm = mb[gh * WW + gw];
            vx = xb[gh * WW + gw];
        }
        sm[0][lh][lw] = vm;
        sm[1][lh][lw] = vx;
    }
    __syncthreads();
    // conv3 (pad=1): center at local (ty+2, tx+2), offsets kh-1
    float s3 = b3[0];
    #pragma unroll
    for (int kh = 0; kh < 3; kh++)
        #pragma unroll
        for (int kw = 0; kw < 3; kw++)
            s3 += sm[0][ty + 1 + kh][tx + 1 + kw] * w3[kh * 3 + kw]
                + sm[1][ty + 1 + kh][tx + 1 + kw] * w3[9 + kh * 3 + kw];
    // conv5 (pad=2): offsets kh-2
    float s5 = b5[0];
    #pragma unroll
    for (int kh = 0; kh < 5; kh++)
        #pragma unroll
        for (int kw = 0; kw < 5; kw++)
            s5 += sm[0][ty + kh][tx + kw] * w5[kh * 5 + kw]
                + sm[1][ty + kh][tx + kw] * w5[25 + kh * 5 + kw];
    float a3 = 1.f / (1.f + expf(-s3));
    float a5 = 1.f / (1.f + expf(-s5));
    float fused = wf[0] * a3 + wf[1] * a5 + bf[0];
    float f = 0.2f + 0.8f * fused;
    int gh = h0 + ty, gw = w0 + tx;
    size_t po = (size_t)b * HW + gh * WW + gw;
    fplane[po] = f;
    float val = f * xrp[po];
    red[tid] = val;
    __syncthreads();
    for (int s = 128; s > 0; s >>= 1) {
        if (tid < s) red[tid] += red[tid + s];
        __syncthreads();
    }
    if (tid == 0) atomicAdd(&sums[b], red[0]);
}

// K3: per-batch channel-attention MLP -> cw[b,c]
__global__ void k3_cw(
    const float* __restrict__ sums, const float* __restrict__ br,
    const float* __restrict__ wc1, const float* __restrict__ bc1,
    const float* __restrict__ wc2, const float* __restrict__ bc2,
    float* __restrict__ cw)
{
    __shared__ float hsh[HIDDEN];
    int b = blockIdx.x;
    int t = threadIdx.x;
    float pooled = sums[b] * (1.0f / HW) + br[0];
    if (t < HIDDEN) hsh[t] = fmaxf(wc1[t] * pooled + bc1[t], 0.f);
    __syncthreads();
    if (t < CH) {
        float acc = bc2[t];
        #pragma unroll
        for (int j = 0; j < HIDDEN; j++) acc += wc2[t * HIDDEN + j] * hsh[j];
        cw[b * CH + t] = 1.f / (1.f + expf(-acc));
    }
}

// K4: out = x * (f * cw + 0.7)
__global__ __launch_bounds__(256) void k4_out(
    const float* __restrict__ x, const float* __restrict__ fplane,
    const float* __restrict__ cw, float* __restrict__ out)
{
    int idx = blockIdx.x * 256 + threadIdx.x;   // [0, BATCH*CH*HW4)
    int p = idx & (HW4 - 1);
    int bc = idx >> 14;      // / HW4
    int b = bc >> 6;
    float s = cw[bc];
    float4 xv = ((const float4*)x)[idx];
    float4 fv = ((const float4*)fplane)[(size_t)b * HW4 + p];
    float4 o;
    o.x = xv.x * (fv.x * s + 0.7f);
    o.y = xv.y * (fv.y * s + 0.7f);
    o.z = xv.z * (fv.z * s + 0.7f);
    o.w = xv.w * (fv.w * s + 0.7f);
    ((float4*)out)[idx] = o;
}

extern "C" void kernel_launch(void* const* d_in, const int* in_sizes, int n_in,
                              void* d_out, int out_size, void* d_ws, size_t ws_size,
                              hipStream_t stream) {
    const float* x   = (const float*)d_in[0];
    const float* w3  = (const float*)d_in[1];
    const float* b3  = (const float*)d_in[2];
    const float* w5  = (const float*)d_in[3];
    const float* b5  = (const float*)d_in[4];
    const float* wf  = (const float*)d_in[5];
    const float* bf  = (const float*)d_in[6];
    const float* wr  = (const float*)d_in[7];
    const float* br  = (const float*)d_in[8];
    const float* wc1 = (const float*)d_in[9];
    const float* bc1 = (const float*)d_in[10];
    const float* wc2 = (const float*)d_in[11];
    const float* bc2 = (const float*)d_in[12];

    float* ws   = (float*)d_ws;
    float* meanp = ws;                       // BATCH*HW
    float* maxp  = ws + (size_t)BATCH * HW;
    float* xrp   = ws + (size_t)2 * BATCH * HW;
    float* fpl   = ws + (size_t)3 * BATCH * HW;
    float* sums  = ws + (size_t)4 * BATCH * HW;  // BATCH floats
    float* cw    = sums + BATCH;                 // BATCH*CH floats

    hipMemsetAsync(sums, 0, BATCH * sizeof(float), stream);

    k1_reduce<<<BATCH * HW4 / 256, 256, 0, stream>>>(x, wr, meanp, maxp, xrp);

    dim3 g2(WW / 16, HH / 16, BATCH);
    k2_fused<<<g2, dim3(16, 16), 0, stream>>>(meanp, maxp, xrp, w3, b3, w5, b5,
                                              wf, bf, fpl, sums);

    k3_cw<<<BATCH, 64, 0, stream>>>(sums, br, wc1, bc1, wc2, bc2, cw);

    k4_out<<<BATCH * CH * HW4 / 256, 256, 0, stream>>>(x, fpl, cw, (float*)d_out);
}

// Round 3
// 563.434 us; speedup vs baseline: 1.0289x; 1.0289x over previous
//
#include <hip/hip_runtime.h>
#include <math.h>

#define BATCH 16
#define CH 64
#define HH 256
#define WW 256
#define HW (HH*WW)     // 65536
#define HW4 (HW/4)     // 16384
#define HIDDEN 32

typedef float nfloat4 __attribute__((ext_vector_type(4)));

// K1: per-pixel channel reductions: mm = (mean, max) interleaved, xr = sum_c wr[c]*x[c]
__global__ __launch_bounds__(256) void msa_k1_reduce(
    const float* __restrict__ x, const float* __restrict__ wr,
    float* __restrict__ mm, float* __restrict__ xrp)
{
    int idx = blockIdx.x * 256 + threadIdx.x;   // [0, BATCH*HW4)
    int b = idx / HW4;
    int p = idx % HW4;
    const float4* xb = (const float4*)x + (size_t)b * CH * HW4 + p;
    float sx = 0.f, sy = 0.f, sz = 0.f, sw = 0.f;
    float mx = -3.4e38f, my = -3.4e38f, mz = -3.4e38f, mw = -3.4e38f;
    float rx = 0.f, ry = 0.f, rz = 0.f, rw = 0.f;
    #pragma unroll 8
    for (int c = 0; c < CH; c++) {
        float4 v = xb[(size_t)c * HW4];
        float w = wr[c];
        sx += v.x; sy += v.y; sz += v.z; sw += v.w;
        mx = fmaxf(mx, v.x); my = fmaxf(my, v.y); mz = fmaxf(mz, v.z); mw = fmaxf(mw, v.w);
        rx += w * v.x; ry += w * v.y; rz += w * v.z; rw += w * v.w;
    }
    const float inv = 1.0f / CH;
    size_t o = (size_t)b * HW4 + p;
    // interleaved (mean,max) pairs: 2 float4 per thread
    float4 mm0 = {sx * inv, mx, sy * inv, my};
    float4 mm1 = {sz * inv, mz, sw * inv, mw};
    ((float4*)mm)[2 * o]     = mm0;
    ((float4*)mm)[2 * o + 1] = mm1;
    float4 xrv = {rx, ry, rz, rw};
    ((float4*)xrp)[o] = xrv;
}

// K2: 3x3 + 5x5 convs over (mean,max) descriptor, sigmoid, 1x1 fuse, scale;
// writes f plane and accumulates sum_b( f * xr ) for the global pool.
__global__ __launch_bounds__(256) void msa_k2_conv(
    const float* __restrict__ mm, const float* __restrict__ xrp,
    const float* __restrict__ w3, const float* __restrict__ b3,
    const float* __restrict__ w5, const float* __restrict__ b5,
    const float* __restrict__ wf, const float* __restrict__ bf,
    float* __restrict__ fplane, float* __restrict__ sums)
{
    __shared__ float sm[2][20][20];   // 16x16 tile + halo 2
    __shared__ float red[256];
    int b = blockIdx.z;
    int h0 = blockIdx.y * 16, w0 = blockIdx.x * 16;
    int tx = threadIdx.x, ty = threadIdx.y;
    int tid = ty * 16 + tx;
    const float2* mb = (const float2*)mm + (size_t)b * HW;
    for (int l = tid; l < 400; l += 256) {
        int lh = l / 20, lw = l % 20;
        int gh = h0 + lh - 2, gw = w0 + lw - 2;
        float vm = 0.f, vx = 0.f;
        if (gh >= 0 && gh < HH && gw >= 0 && gw < WW) {
            float2 v = mb[gh * WW + gw];
            vm = v.x; vx = v.y;
        }
        sm[0][lh][lw] = vm;
        sm[1][lh][lw] = vx;
    }
    __syncthreads();
    // conv3 (pad=1): center at local (ty+2, tx+2)
    float s3 = b3[0];
    #pragma unroll
    for (int kh = 0; kh < 3; kh++)
        #pragma unroll
        for (int kw = 0; kw < 3; kw++)
            s3 += sm[0][ty + 1 + kh][tx + 1 + kw] * w3[kh * 3 + kw]
                + sm[1][ty + 1 + kh][tx + 1 + kw] * w3[9 + kh * 3 + kw];
    // conv5 (pad=2)
    float s5 = b5[0];
    #pragma unroll
    for (int kh = 0; kh < 5; kh++)
        #pragma unroll
        for (int kw = 0; kw < 5; kw++)
            s5 += sm[0][ty + kh][tx + kw] * w5[kh * 5 + kw]
                + sm[1][ty + kh][tx + kw] * w5[25 + kh * 5 + kw];
    float a3 = 1.f / (1.f + expf(-s3));
    float a5 = 1.f / (1.f + expf(-s5));
    float fused = wf[0] * a3 + wf[1] * a5 + bf[0];
    float f = 0.2f + 0.8f * fused;
    int gh = h0 + ty, gw = w0 + tx;
    size_t po = (size_t)b * HW + gh * WW + gw;
    fplane[po] = f;
    red[tid] = f * xrp[po];
    __syncthreads();
    for (int s = 128; s > 0; s >>= 1) {
        if (tid < s) red[tid] += red[tid + s];
        __syncthreads();
    }
    if (tid == 0) atomicAdd(&sums[b], red[0]);
}

// K3: per-batch channel-attention MLP -> cw[b,c]
__global__ void msa_k3_cw(
    const float* __restrict__ sums, const float* __restrict__ br,
    const float* __restrict__ wc1, const float* __restrict__ bc1,
    const float* __restrict__ wc2, const float* __restrict__ bc2,
    float* __restrict__ cw)
{
    __shared__ float hsh[HIDDEN];
    int b = blockIdx.x;
    int t = threadIdx.x;
    float pooled = sums[b] * (1.0f / HW) + br[0];
    if (t < HIDDEN) hsh[t] = fmaxf(wc1[t] * pooled + bc1[t], 0.f);
    __syncthreads();
    if (t < CH) {
        float acc = bc2[t];
        #pragma unroll
        for (int j = 0; j < HIDDEN; j++) acc += wc2[t * HIDDEN + j] * hsh[j];
        cw[b * CH + t] = 1.f / (1.f + expf(-acc));
    }
}

// K4: out = x * (f * cw + 0.7). Reversed block order: consume the MRU tail of x
// that K1 left in L3 first. Non-temporal stores so out doesn't evict x.
__global__ __launch_bounds__(256) void msa_k4_out(
    const float* __restrict__ x, const float* __restrict__ fplane,
    const float* __restrict__ cw, float* __restrict__ out)
{
    int bi = gridDim.x - 1 - blockIdx.x;           // reverse traversal
    int idx = bi * 256 + threadIdx.x;              // [0, BATCH*CH*HW4)
    int p = idx & (HW4 - 1);
    int bc = idx >> 14;      // / HW4
    int b = bc >> 6;
    float s = cw[bc];
    float4 xv = ((const float4*)x)[idx];
    float4 fv = ((const float4*)fplane)[(size_t)b * HW4 + p];
    nfloat4 o;
    o.x = xv.x * (fv.x * s + 0.7f);
    o.y = xv.y * (fv.y * s + 0.7f);
    o.z = xv.z * (fv.z * s + 0.7f);
    o.w = xv.w * (fv.w * s + 0.7f);
    __builtin_nontemporal_store(o, ((nfloat4*)out) + idx);
}

extern "C" void kernel_launch(void* const* d_in, const int* in_sizes, int n_in,
                              void* d_out, int out_size, void* d_ws, size_t ws_size,
                              hipStream_t stream) {
    const float* x   = (const float*)d_in[0];
    const float* w3  = (const float*)d_in[1];
    const float* b3  = (const float*)d_in[2];
    const float* w5  = (const float*)d_in[3];
    const float* b5  = (const float*)d_in[4];
    const float* wf  = (const float*)d_in[5];
    const float* bf  = (const float*)d_in[6];
    const float* wr  = (const float*)d_in[7];
    const float* br  = (const float*)d_in[8];
    const float* wc1 = (const float*)d_in[9];
    const float* bc1 = (const float*)d_in[10];
    const float* wc2 = (const float*)d_in[11];
    const float* bc2 = (const float*)d_in[12];

    float* ws    = (float*)d_ws;
    float* mm    = ws;                               // BATCH*HW*2 (mean,max pairs)
    float* xrp   = ws + (size_t)2 * BATCH * HW;      // BATCH*HW
    float* fpl   = ws + (size_t)3 * BATCH * HW;      // BATCH*HW
    float* sums  = ws + (size_t)4 * BATCH * HW;      // BATCH floats
    float* cw    = sums + BATCH;                     // BATCH*CH floats

    (void)hipMemsetAsync(sums, 0, BATCH * sizeof(float), stream);

    msa_k1_reduce<<<BATCH * HW4 / 256, 256, 0, stream>>>(x, wr, mm, xrp);

    dim3 g2(WW / 16, HH / 16, BATCH);
    msa_k2_conv<<<g2, dim3(16, 16), 0, stream>>>(mm, xrp, w3, b3, w5, b5,
                                                 wf, bf, fpl, sums);

    msa_k3_cw<<<BATCH, 64, 0, stream>>>(sums, br, wc1, bc1, wc2, bc2, cw);

    msa_k4_out<<<BATCH * CH * HW4 / 256, 256, 0, stream>>>(x, fpl, cw, (float*)d_out);
}